// Round 5
// baseline (49.809 us; speedup 1.0000x reference)
//
#include <hip/hip_runtime.h>

// Overlap-add: y[b, f*256 + c] += x[b, c, f]
// x: [16, 1024, 2048] f32, y: [16, 525056] f32
// WIN/HOP = 4 -> y[b, g*256 + r] = sum_{k=0}^{3} x[b, k*256 + r, g - k]  (valid g-k)
//
// R5: (a) LDS column swizzle col = j ^ (rl & 24): phase-2 gather becomes
// exactly 2-way (free), phase-1 b128 writes stay contiguous/aligned.
// (b) 2 units (rsp, rsp+4) per block pipelined through one LDS buffer:
// unit B's first load batch is issued before phase2(A) so its HBM latency
// hides under the stores. (c) nontemporal y stores.

constexpr int BATCH   = 16;
constexpr int WIN     = 1024;
constexpr int HOP     = 256;
constexpr int NF      = 2048;                      // frames
constexpr int OUT_LEN = (NF - 1) * HOP + WIN;      // 525056
constexpr int GTOT    = OUT_LEN / HOP;             // 2051
constexpr int FT      = 128;                       // g-values per tile
constexpr int NTILES  = (GTOT + FT - 1) / FT;      // 17
constexpr int RB      = 32;                        // r-values per unit
constexpr int NPAIR   = HOP / RB / 2;              // 4 rsp-pairs
constexpr int RS2     = FT + 4;                    // 132 floats (528B, 16B-aligned rows)

// alignment-4 float4: the per-k shift (-k floats) misaligns 16B vectors
typedef float f4u __attribute__((ext_vector_type(4), aligned(4)));
// 16B-aligned float4 for LDS accesses / global stores
typedef float f4a __attribute__((ext_vector_type(4), aligned(16)));

__global__ __launch_bounds__(256, 8)
void oadd_kernel(const float* __restrict__ x, float* __restrict__ y) {
    // accT2[rl][col], col = j ^ (rl & 24)
    __shared__ __align__(16) float accT2[RB][RS2];   // 16896 B -> 8 blocks/CU

    const int tid  = threadIdx.x;
    const int tile = blockIdx.x;
    const int pr   = blockIdx.y;
    const int b    = blockIdx.z;
    const int g0   = tile * FT;
    const int rbaseA = pr * RB;                // 0,32,64,96
    const int rbaseB = rbaseA + (HOP / 2);     // 128,160,192,224

    const int lane = tid & 63;
    const int w    = tid >> 6;            // wave 0..3
    const int fq   = (lane & 31) * 4;     // f-chunk within tile: 0..124
    const int rh   = lane >> 5;           // row half 0/1
    const int rlw  = w * 2 + rh;          // row-in-group base

    const int c4 = (tid & 7) * 4;         // r-quad for phase 2
    const int jj = tid >> 3;              // j-lane for phase 2 (0..31)

    const float* __restrict__ xb = x + (size_t)b * WIN * NF;
    float* __restrict__ yb = y + (size_t)b * OUT_LEN;

    // interior iff all f = g0 + j - k (j in [0,FT), k in [0,4)) are in [0,NF)
    const bool interior = (g0 >= 3) && (g0 + FT <= NF);

    auto loadBatch = [&](int rbase, int ip, f4u (&v)[2][4]) {
        #pragma unroll
        for (int i2 = 0; i2 < 2; ++i2) {
            const int rl = (ip * 2 + i2) * 8 + rlw;
            const float* rp = xb + (size_t)(rbase + rl) * NF + (g0 + fq);
            #pragma unroll
            for (int k = 0; k < 4; ++k)
                v[i2][k] = *reinterpret_cast<const f4u*>(rp + (size_t)(k * HOP) * NF - k);
        }
    };
    auto sumStore = [&](int ip, f4u (&v)[2][4]) {
        #pragma unroll
        for (int i2 = 0; i2 < 2; ++i2) {
            const int rl = (ip * 2 + i2) * 8 + rlw;
            f4u s = (v[i2][0] + v[i2][1]) + (v[i2][2] + v[i2][3]);
            *reinterpret_cast<f4a*>(&accT2[rl][fq ^ (rl & 24)]) = s;
        }
    };
    auto phase2 = [&](int rbase) {
        #pragma unroll
        for (int pass = 0; pass < 4; ++pass) {
            const int j = pass * 32 + jj;
            const int g = g0 + j;
            if (g < GTOT) {
                f4a v;
                v.x = accT2[c4 + 0][j ^ ((c4 + 0) & 24)];
                v.y = accT2[c4 + 1][j ^ ((c4 + 1) & 24)];
                v.z = accT2[c4 + 2][j ^ ((c4 + 2) & 24)];
                v.w = accT2[c4 + 3][j ^ ((c4 + 3) & 24)];
                __builtin_nontemporal_store(
                    v, reinterpret_cast<f4a*>(&yb[(size_t)g * HOP + rbase + c4]));
            }
        }
    };
    auto phase1Guarded = [&](int rbase) {
        #pragma unroll
        for (int it = 0; it < 4; ++it) {
            const int rl = it * 8 + rlw;
            const int r  = rbase + rl;
            float a[4] = {0.f, 0.f, 0.f, 0.f};
            #pragma unroll
            for (int k = 0; k < 4; ++k) {
                const float* rp = xb + (size_t)(k * HOP + r) * NF;
                const int f0 = g0 + fq - k;
                if (f0 >= 0 && f0 + 3 < NF) {
                    f4u vv = *reinterpret_cast<const f4u*>(rp + f0);
                    a[0] += vv.x; a[1] += vv.y; a[2] += vv.z; a[3] += vv.w;
                } else {
                    #pragma unroll
                    for (int m = 0; m < 4; ++m) {
                        const int f = f0 + m;
                        if (f >= 0 && f < NF) a[m] += rp[f];
                    }
                }
            }
            const int base = fq ^ (rl & 24);
            accT2[rl][base + 0] = a[0];
            accT2[rl][base + 1] = a[1];
            accT2[rl][base + 2] = a[2];
            accT2[rl][base + 3] = a[3];
        }
    };

    if (interior) {
        // ---- unit A phase 1 ----
        {
            f4u v[2][4];
            loadBatch(rbaseA, 0, v); sumStore(0, v);
            loadBatch(rbaseA, 1, v); sumStore(1, v);
        }
        __syncthreads();
        // ---- issue B batch 0, drain phase2(A) over it ----
        f4u vb[2][4];
        loadBatch(rbaseB, 0, vb);
        phase2(rbaseA);
        __syncthreads();                 // phase2(A) reads done before overwrite
        // ---- unit B phase 1 (batch 0 already landed) ----
        sumStore(0, vb);
        loadBatch(rbaseB, 1, vb);
        sumStore(1, vb);
        __syncthreads();
        phase2(rbaseB);
    } else {
        // boundary tiles (0 and 16): guarded, unpipelined
        phase1Guarded(rbaseA);
        __syncthreads();
        phase2(rbaseA);
        __syncthreads();
        phase1Guarded(rbaseB);
        __syncthreads();
        phase2(rbaseB);
    }
}

extern "C" void kernel_launch(void* const* d_in, const int* in_sizes, int n_in,
                              void* d_out, int out_size, void* d_ws, size_t ws_size,
                              hipStream_t stream) {
    const float* x = (const float*)d_in[0];
    float* y = (float*)d_out;
    dim3 grid(NTILES, NPAIR, BATCH);
    oadd_kernel<<<grid, 256, 0, stream>>>(x, y);
}

// Round 6
// 43.494 us; speedup vs baseline: 1.1452x; 1.1452x over previous
//
#include <hip/hip_runtime.h>

// Overlap-add: y[b, f*256 + c] += x[b, c, f]
// x: [16, 1024, 2048] f32, y: [16, 525056] f32
// WIN/HOP = 4 -> y[b, g*256 + r] = sum_{k=0}^{3} x[b, k*256 + r, g - k]  (valid g-k)
//
// R6 = R4 skeleton (best: 41.9us) + LDS XOR swizzle (col = j ^ (rl&24),
// phase-2 gather exactly 2-way = free) + nontemporal y stores + guard hoist.
// R5's pipeline variant regressed (VGPR 64->32, loads serialized) - reverted.

constexpr int BATCH   = 16;
constexpr int WIN     = 1024;
constexpr int HOP     = 256;
constexpr int NF      = 2048;                      // frames
constexpr int OUT_LEN = (NF - 1) * HOP + WIN;      // 525056
constexpr int GTOT    = OUT_LEN / HOP;             // 2051
constexpr int FT      = 128;                       // g-values per tile
constexpr int NTILES  = (GTOT + FT - 1) / FT;      // 17
constexpr int RB      = 32;                        // r-values per block
constexpr int NRS     = HOP / RB;                  // 8
constexpr int RS2     = FT + 4;                    // 132 floats (528B, 16B-aligned rows)

// alignment-4 float4: the per-k shift (-k floats) misaligns 16B vectors
typedef float f4u __attribute__((ext_vector_type(4), aligned(4)));
// 16B-aligned float4 for LDS accesses / global stores
typedef float f4a __attribute__((ext_vector_type(4), aligned(16)));

__global__ __launch_bounds__(256, 8)
void oadd_kernel(const float* __restrict__ x, float* __restrict__ y) {
    // accT2[rl][col], col = j ^ (rl & 24)
    __shared__ __align__(16) float accT2[RB][RS2];   // 16896 B -> 8 blocks/CU

    const int tid   = threadIdx.x;
    const int tile  = blockIdx.x;
    const int rsp   = blockIdx.y;
    const int b     = blockIdx.z;
    const int g0    = tile * FT;
    const int rbase = rsp * RB;

    const int lane = tid & 63;
    const int w    = tid >> 6;            // wave 0..3
    const int fq   = (lane & 31) * 4;     // f-chunk within tile: 0..124
    const int rh   = lane >> 5;           // row half: 0/1 (wave = 2 rows x 512B)

    const float* __restrict__ xb = x + (size_t)b * WIN * NF;

    // interior iff all f = g0 + j - k (j in [0,FT), k in [0,4)) are in [0,NF)
    const bool interior = (g0 >= 3) && (g0 + FT - 1 <= NF - 1);

    if (interior) {
        #pragma unroll
        for (int ip = 0; ip < 2; ++ip) {
            // batch: 8 fully-independent loads (2 row-groups x 4 shifts)
            f4u v[2][4];
            #pragma unroll
            for (int i2 = 0; i2 < 2; ++i2) {
                const int it = ip * 2 + i2;
                const int rl = it * 8 + w * 2 + rh;
                const float* rp = xb + (size_t)(rbase + rl) * NF + (g0 + fq);
                #pragma unroll
                for (int k = 0; k < 4; ++k) {
                    v[i2][k] = *reinterpret_cast<const f4u*>(rp + (size_t)(k * HOP) * NF - k);
                }
            }
            #pragma unroll
            for (int i2 = 0; i2 < 2; ++i2) {
                const int it = ip * 2 + i2;
                const int rl = it * 8 + w * 2 + rh;
                f4u s = (v[i2][0] + v[i2][1]) + (v[i2][2] + v[i2][3]);
                *reinterpret_cast<f4a*>(&accT2[rl][fq ^ (rl & 24)]) = s;
            }
        }
    } else {
        // boundary tiles (0 and 16): per-lane guards, vector load when safe
        #pragma unroll
        for (int it = 0; it < 4; ++it) {
            const int rl = it * 8 + w * 2 + rh;
            const int r  = rbase + rl;
            float a[4] = {0.f, 0.f, 0.f, 0.f};
            #pragma unroll
            for (int k = 0; k < 4; ++k) {
                const float* rp = xb + (size_t)(k * HOP + r) * NF;
                const int f0 = g0 + fq - k;
                if (f0 >= 0 && f0 + 3 <= NF - 1) {
                    f4u vv = *reinterpret_cast<const f4u*>(rp + f0);
                    a[0] += vv.x; a[1] += vv.y; a[2] += vv.z; a[3] += vv.w;
                } else {
                    #pragma unroll
                    for (int m = 0; m < 4; ++m) {
                        const int f = f0 + m;
                        if (f >= 0 && f < NF) a[m] += rp[f];
                    }
                }
            }
            const int base = fq ^ (rl & 24);
            accT2[rl][base + 0] = a[0];
            accT2[rl][base + 1] = a[1];
            accT2[rl][base + 2] = a[2];
            accT2[rl][base + 3] = a[3];
        }
    }

    __syncthreads();

    // write-out: thread gathers 4 consecutive rl for one j -> 128B-coalesced
    // nontemporal f4 stores. Swizzled gather is exactly 2-way per bank (free).
    float* __restrict__ yb = y + (size_t)b * OUT_LEN;
    const int c4 = (tid & 7) * 4;     // 0..28
    const int jj = tid >> 3;          // 0..31
    if (interior) {
        #pragma unroll
        for (int pass = 0; pass < 4; ++pass) {
            const int j = pass * 32 + jj;                  // g0+j <= 2047 < GTOT always
            f4a v;
            v.x = accT2[c4 + 0][j ^ ((c4 + 0) & 24)];
            v.y = accT2[c4 + 1][j ^ ((c4 + 1) & 24)];
            v.z = accT2[c4 + 2][j ^ ((c4 + 2) & 24)];
            v.w = accT2[c4 + 3][j ^ ((c4 + 3) & 24)];
            __builtin_nontemporal_store(
                v, reinterpret_cast<f4a*>(&yb[(size_t)(g0 + j) * HOP + rbase + c4]));
        }
    } else {
        #pragma unroll
        for (int pass = 0; pass < 4; ++pass) {
            const int j = pass * 32 + jj;
            const int g = g0 + j;
            if (g < GTOT) {
                f4a v;
                v.x = accT2[c4 + 0][j ^ ((c4 + 0) & 24)];
                v.y = accT2[c4 + 1][j ^ ((c4 + 1) & 24)];
                v.z = accT2[c4 + 2][j ^ ((c4 + 2) & 24)];
                v.w = accT2[c4 + 3][j ^ ((c4 + 3) & 24)];
                __builtin_nontemporal_store(
                    v, reinterpret_cast<f4a*>(&yb[(size_t)g * HOP + rbase + c4]));
            }
        }
    }
}

extern "C" void kernel_launch(void* const* d_in, const int* in_sizes, int n_in,
                              void* d_out, int out_size, void* d_ws, size_t ws_size,
                              hipStream_t stream) {
    const float* x = (const float*)d_in[0];
    float* y = (float*)d_out;
    dim3 grid(NTILES, NRS, BATCH);
    oadd_kernel<<<grid, 256, 0, stream>>>(x, y);
}

// Round 7
// 40.890 us; speedup vs baseline: 1.2181x; 1.0637x over previous
//
#include <hip/hip_runtime.h>

// Overlap-add: y[b, f*256 + c] += x[b, c, f]
// x: [16, 1024, 2048] f32, y: [16, 525056] f32
// WIN/HOP = 4 -> y[b, g*256 + r] = sum_{k=0}^{3} x[b, k*256 + r, g - k]
//
// R7: phase 1 = pure global_load_lds DMA (no VGPR round-trip, 16 outstanding
// 16B DMAs/thread, ~128 KB in flight per CU). k-sum moved to phase 2 LDS
// reads (bank = j%32, 2 lanes/bank = conflict-free). LDS linear (DMA dest
// constraint), 64 KB -> 2 blocks/CU.

constexpr int BATCH   = 16;
constexpr int WIN     = 1024;
constexpr int HOP     = 256;
constexpr int NF      = 2048;                      // frames
constexpr int OUT_LEN = (NF - 1) * HOP + WIN;      // 525056
constexpr int GTOT    = OUT_LEN / HOP;             // 2051
constexpr int FT      = 128;                       // g-values per tile
constexpr int NTILES  = (GTOT + FT - 1) / FT;      // 17
constexpr int RB      = 32;                        // r-values per block
constexpr int NRS     = HOP / RB;                  // 8

typedef float f4a __attribute__((ext_vector_type(4), aligned(16)));

__global__ __launch_bounds__(256, 2)
void oadd_kernel(const float* __restrict__ x, float* __restrict__ y) {
    // L[k][rl][j] holds x[b, k*256 + rbase+rl, g0 + j - k] (0 if OOB)
    __shared__ float L[4][RB][FT];                 // 65536 B -> 2 blocks/CU

    const int tid   = threadIdx.x;
    const int tile  = blockIdx.x;
    const int rsp   = blockIdx.y;
    const int b     = blockIdx.z;
    const int g0    = tile * FT;
    const int rbase = rsp * RB;

    const int lane = tid & 63;
    const int w    = tid >> 6;            // wave 0..3
    const int fq   = (lane & 31) * 4;     // f-chunk: 0..124
    const int rh   = lane >> 5;           // row half 0/1

    const float* __restrict__ xb = x + (size_t)b * WIN * NF;

    // interior iff all f = g0 + j - k (j in [0,FT), k in [0,4)) are in [0,NF)
    const bool interior = (g0 >= 3) && (g0 + FT <= NF);

    if (interior) {
        // fire-and-forget: 16 direct-to-LDS DMAs per thread, no waits between.
        // dest is wave-uniform base + lane*16: lanes 0..31 fill row rl,
        // lanes 32..63 fill row rl+1 (rows contiguous, 512 B each).
        #pragma unroll
        for (int it = 0; it < 4; ++it) {
            const int rl = it * 8 + w * 2;         // wave-uniform
            #pragma unroll
            for (int k = 0; k < 4; ++k) {
                const float* src = xb + (size_t)(k * HOP + rbase + rl + rh) * NF
                                      + (g0 + fq - k);
                __builtin_amdgcn_global_load_lds(
                    (const __attribute__((address_space(1))) unsigned int*)src,
                    (__attribute__((address_space(3))) unsigned int*)&L[k][rl][0],
                    16, 0, 0);
            }
        }
    } else {
        // boundary tiles (0 and 16): guarded scalar loads, zero-fill OOB
        #pragma unroll
        for (int it = 0; it < 4; ++it) {
            const int rl = it * 8 + w * 2 + rh;
            #pragma unroll
            for (int k = 0; k < 4; ++k) {
                const float* rp = xb + (size_t)(k * HOP + rbase + rl) * NF;
                #pragma unroll
                for (int m = 0; m < 4; ++m) {
                    const int f = g0 + fq + m - k;
                    L[k][rl][fq + m] = (f >= 0 && f < NF) ? rp[f] : 0.f;
                }
            }
        }
    }

    __syncthreads();   // drains vmcnt(0): all DMAs landed

    // phase 2: k-sum + transpose-out. bank = j%32 -> 2 lanes/bank (free).
    float* __restrict__ yb = y + (size_t)b * OUT_LEN;
    const int jj = tid & 31;
    const int rq = tid >> 5;              // 0..7 -> r-quad rq*4..rq*4+3
    #pragma unroll
    for (int p = 0; p < 4; ++p) {
        const int j = p * 32 + jj;
        const int g = g0 + j;
        if (g < GTOT) {
            f4a v;
            #pragma unroll
            for (int m = 0; m < 4; ++m) {
                const int rl = rq * 4 + m;
                v[m] = (L[0][rl][j] + L[1][rl][j]) + (L[2][rl][j] + L[3][rl][j]);
            }
            *reinterpret_cast<f4a*>(&yb[(size_t)g * HOP + rbase + rq * 4]) = v;
        }
    }
}

extern "C" void kernel_launch(void* const* d_in, const int* in_sizes, int n_in,
                              void* d_out, int out_size, void* d_ws, size_t ws_size,
                              hipStream_t stream) {
    const float* x = (const float*)d_in[0];
    float* y = (float*)d_out;
    dim3 grid(NTILES, NRS, BATCH);
    oadd_kernel<<<grid, 256, 0, stream>>>(x, y);
}

// Round 8
// 40.703 us; speedup vs baseline: 1.2237x; 1.0046x over previous
//
#include <hip/hip_runtime.h>

// Overlap-add: y[b, f*256 + c] += x[b, c, f]
// x: [16, 1024, 2048] f32, y: [16, 525056] f32
// WIN/HOP = 4 -> y[b, g*256 + r] = sum_{k=0}^{3} x[b, k*256 + r, g - k]
//
// R8: 2-deep software pipeline per block (T3/T4 minimum-2-phase):
//   issue DMA(A,buf0); issue DMA(B,buf1); vmcnt(8); barrier; phase2(A);
//   vmcnt(0); barrier; phase2(B).
// Counted vmcnt keeps item B's global_load_lds in flight ACROSS the first
// barrier, so B's HBM drain overlaps A's LDS k-sum + stores (removes the
// vmcnt(0)-at-__syncthreads memory-idle window of R4/R7).

constexpr int BATCH   = 16;
constexpr int WIN     = 1024;
constexpr int HOP     = 256;
constexpr int NF      = 2048;                       // frames
constexpr int OUT_LEN = (NF - 1) * HOP + WIN;       // 525056
constexpr int GTOT    = OUT_LEN / HOP;              // 2051
constexpr int FT      = 64;                         // g-values per item
constexpr int NTILE   = (GTOT + FT - 1) / FT;       // 33
constexpr int RB      = 32;                         // r-values per item
constexpr int NRS     = HOP / RB;                   // 8
constexpr int NITEMS  = NTILE * NRS * BATCH;        // 4224
constexpr int NBLK    = NITEMS / 2;                 // 2112 blocks, 2 items each

typedef float f4a __attribute__((ext_vector_type(4), aligned(16)));

__global__ __launch_bounds__(256, 2)
void oadd_kernel(const float* __restrict__ x, float* __restrict__ y) {
    // L[s][k][rl][j] = x[b, k*256 + rbase+rl, g0 + j - k]; two 32KB buffers
    __shared__ float L[2][4][RB][FT];               // 65536 B -> 2 blocks/CU

    const int tid  = threadIdx.x;
    const int lane = tid & 63;
    const int w    = tid >> 6;             // wave 0..3
    const int fq   = (lane & 15) * 4;      // col chunk 0..60
    const int sr   = lane >> 4;            // sub-row 0..3

    // decode the two items (linear id: tile fastest, then rsp, then b)
    const int it0 = blockIdx.x * 2;
    const int it1 = it0 + 1;
    const int tA = it0 % NTILE, rA = (it0 / NTILE) & 7, bA = it0 / (NTILE * 8);
    const int tB = it1 % NTILE, rB = (it1 / NTILE) & 7, bB = it1 / (NTILE * 8);
    const int g0A = tA * FT, rbaseA = rA * RB;
    const int g0B = tB * FT, rbaseB = rB * RB;
    const float* __restrict__ xbA = x + (size_t)bA * WIN * NF;
    const float* __restrict__ xbB = x + (size_t)bB * WIN * NF;
    float* __restrict__ ybA = y + (size_t)bA * OUT_LEN;
    float* __restrict__ ybB = y + (size_t)bB * OUT_LEN;
    const bool intA = (g0A >= 3) && (g0A + FT <= NF);
    const bool intB = (g0B >= 3) && (g0B + FT <= NF);

    // ---- fill: 8 fire-and-forget 1KB DMAs per wave (4 rows x 256B each) ----
    auto fillDMA = [&](int s, int g0, int rbase, const float* __restrict__ xb) {
        #pragma unroll
        for (int i = 0; i < 8; ++i) {
            const int p   = w * 8 + i;     // 0..31
            const int k   = p >> 3;        // 0..3
            const int rl0 = (p & 7) * 4;   // 0,4,..,28
            // lane l: src row rl0+sr (shifted window -k), dest = base + l*16
            const float* src = xb + (size_t)(k * HOP + rbase + rl0 + sr) * NF
                                  + (g0 + fq - k);
            __builtin_amdgcn_global_load_lds(
                (const __attribute__((address_space(1))) unsigned int*)src,
                (__attribute__((address_space(3))) unsigned int*)&L[s][k][rl0][0],
                16, 0, 0);
        }
    };
    // ---- guarded fill for boundary tiles (g0=0 / last): VGPR path ----
    auto fillGuard = [&](int s, int g0, int rbase, const float* __restrict__ xb) {
        #pragma unroll
        for (int i = 0; i < 8; ++i) {
            const int p  = w * 8 + i;
            const int k  = p >> 3;
            const int rl = (p & 7) * 4 + sr;
            const float* rp = xb + (size_t)(k * HOP + rbase + rl) * NF;
            #pragma unroll
            for (int m = 0; m < 4; ++m) {
                const int f = g0 + fq + m - k;
                L[s][k][rl][fq + m] = (f >= 0 && f < NF) ? rp[f] : 0.f;
            }
        }
        asm volatile("s_waitcnt lgkmcnt(0)" ::: "memory");  // ds_writes visible pre-barrier
    };
    // ---- phase 2: k-sum + transpose-out (bank = j%32, 2 lanes/bank = free) ----
    auto phase2 = [&](int s, int g0, int rbase, float* __restrict__ yb) {
        const int jj = tid & 31;
        const int rq = tid >> 5;           // 0..7
        #pragma unroll
        for (int p = 0; p < 2; ++p) {
            const int j = p * 32 + jj;
            const int g = g0 + j;
            if (g < GTOT) {
                f4a v;
                #pragma unroll
                for (int m = 0; m < 4; ++m) {
                    const int rl = rq * 4 + m;
                    v[m] = (L[s][0][rl][j] + L[s][1][rl][j])
                         + (L[s][2][rl][j] + L[s][3][rl][j]);
                }
                *reinterpret_cast<f4a*>(&yb[(size_t)g * HOP + rbase + rq * 4]) = v;
            }
        }
    };

    // ---- 2-deep pipeline ----
    if (intA) fillDMA(0, g0A, rbaseA, xbA); else fillGuard(0, g0A, rbaseA, xbA);
    if (intB) fillDMA(1, g0B, rbaseB, xbB); else fillGuard(1, g0B, rbaseB, xbB);

    // wait for A's DMAs only: B's 8 stay in flight across the barrier
    if (intB) { asm volatile("s_waitcnt vmcnt(8)" ::: "memory"); }
    else      { asm volatile("s_waitcnt vmcnt(0)" ::: "memory"); }
    __builtin_amdgcn_s_barrier();
    __builtin_amdgcn_sched_barrier(0);

    phase2(0, g0A, rbaseA, ybA);           // B's drain hides under this

    asm volatile("s_waitcnt vmcnt(0)" ::: "memory");
    __builtin_amdgcn_s_barrier();
    __builtin_amdgcn_sched_barrier(0);

    phase2(1, g0B, rbaseB, ybB);
}

extern "C" void kernel_launch(void* const* d_in, const int* in_sizes, int n_in,
                              void* d_out, int out_size, void* d_ws, size_t ws_size,
                              hipStream_t stream) {
    const float* x = (const float*)d_in[0];
    float* y = (float*)d_out;
    oadd_kernel<<<dim3(NBLK), 256, 0, stream>>>(x, y);
}

// Round 9
// 37.136 us; speedup vs baseline: 1.3412x; 1.0961x over previous
//
#include <hip/hip_runtime.h>

// Overlap-add: y[b, f*256 + c] += x[b, c, f]
// x: [16, 1024, 2048] f32, y: [16, 525056] f32
// WIN/HOP = 4 -> y[b, g*256 + r] = sum_{k=0}^{3} x[b, k*256 + r, g - k]
//
// R9: persistent blocks, steady-state 2-deep DMA pipeline over a 4-buffer
// LDS rotation. Per item: fill(t+2) -> s_waitcnt vmcnt(8) -> s_barrier ->
// phase2(t). vmcnt never drains to 0 mid-stream; cold-start latency paid
// once per block (16+ items) instead of per 2 items (R8).
// All items are DMA-uniform: tile 0 masks invalid k-terms in phase2,
// tile 32 (last) uses a clamped source window + shifted LDS remap.

constexpr int BATCH   = 16;
constexpr int WIN     = 1024;
constexpr int HOP     = 256;
constexpr int NF      = 2048;                       // frames
constexpr int OUT_LEN = (NF - 1) * HOP + WIN;       // 525056
constexpr int GTOT    = OUT_LEN / HOP;              // 2051
constexpr int FT      = 64;                         // g-values per item
constexpr int NTILE   = (GTOT + FT - 1) / FT;       // 33 (tile 32: j<3 valid)
constexpr int RB      = 16;                         // r-values per item
constexpr int NRS     = HOP / RB;                   // 16
constexpr int NITEMS  = NTILE * NRS * BATCH;        // 8448
constexpr int NBLK    = 512;                        // 2 blocks/CU exactly
constexpr int NBUF    = 4;                          // 4 x 16KB = 64KB LDS

typedef float f4a __attribute__((ext_vector_type(4), aligned(16)));

__global__ __launch_bounds__(256, 2)
void oadd_kernel(const float* __restrict__ x, float* __restrict__ y) {
    // L[s][k][rl][j] = x[b, k*256 + rbase+rl, g0 + j - k]  (per-mode remaps)
    __shared__ float L[NBUF][4][RB][FT];            // 65536 B

    const int tid = threadIdx.x;
    const int w   = tid >> 6;          // wave id == k handled by this wave
    const int l   = tid & 63;
    const int sr  = l >> 4;            // sub-row 0..3 within a 1KB DMA
    const int c4  = (l & 15) * 4;      // col 0..60 within a 256B row

    const int j   = tid & 63;          // phase2: output g-offset
    const int rq  = tid >> 6;          // phase2: r-quad 0..3

    // items handled by this block: it = bid + t*NBLK, t in [0, T)
    const int rem = NITEMS - (NITEMS / NBLK) * NBLK;              // 256
    const int T   = (int)blockIdx.x < rem ? NITEMS / NBLK + 1 : NITEMS / NBLK;

    auto decode = [&](int t, int& g0, int& rbase, int& b, int& mode) {
        const unsigned it   = blockIdx.x + (unsigned)t * NBLK;
        const unsigned tile = it % NTILE;
        const unsigned rest = it / NTILE;
        const unsigned rsp  = rest % NRS;
        b     = rest / NRS;
        g0    = tile * FT;
        rbase = rsp * RB;
        mode  = (tile == 0) ? 1 : ((tile == NTILE - 1) ? 2 : 0);
    };

    // fill: wave w DMAs the k=w slab (16 rows x 256B) as 4 x 1KB instructions
    auto fill = [&](int t, int s) {
        int g0, rbase, b, mode; decode(t, g0, rbase, b, mode);
        // mode 2 (last tile): clamp window start to NF-FT; phase2 remaps.
        // mode 1 (tile 0): g0+c4-w dips up to 3 floats into the previous
        // row's tail (in-bounds garbage); phase2 masks those terms.
        const int fcol = (mode == 2) ? (NF - FT) + c4 : g0 + c4 - w;
        const float* src0 = x + (size_t)b * WIN * NF
                              + (size_t)(w * HOP + rbase + sr) * NF + fcol;
        #pragma unroll
        for (int i = 0; i < 4; ++i) {
            __builtin_amdgcn_global_load_lds(
                (const __attribute__((address_space(1))) unsigned int*)(src0 + (size_t)(4 * i) * NF),
                (__attribute__((address_space(3))) unsigned int*)&L[s][w][4 * i][0],
                16, 0, 0);
        }
    };

    // phase2: k-sum + transpose-out. bank = j%32 -> 2 lanes/bank (free).
    auto phase2 = [&](int t, int s) {
        int g0, rbase, b, mode; decode(t, g0, rbase, b, mode);
        float* __restrict__ yb = y + (size_t)b * OUT_LEN;
        if (mode == 0) {
            f4a v;
            #pragma unroll
            for (int m = 0; m < 4; ++m) {
                const int rl = rq * 4 + m;
                v[m] = (L[s][0][rl][j] + L[s][1][rl][j])
                     + (L[s][2][rl][j] + L[s][3][rl][j]);
            }
            *reinterpret_cast<f4a*>(&yb[(size_t)(g0 + j) * HOP + rbase + rq * 4]) = v;
        } else if (mode == 1) {
            f4a v;
            #pragma unroll
            for (int m = 0; m < 4; ++m) {
                const int rl = rq * 4 + m;
                float a = L[s][0][rl][j];
                a += (j >= 1) ? L[s][1][rl][j] : 0.f;
                a += (j >= 2) ? L[s][2][rl][j] : 0.f;
                a += (j >= 3) ? L[s][3][rl][j] : 0.f;
                v[m] = a;
            }
            *reinterpret_cast<f4a*>(&yb[(size_t)(g0 + j) * HOP + rbase + rq * 4]) = v;
        } else {
            // last tile: valid g only for j < 3; L[s][k] holds window
            // [NF-FT, NF): wanted f = g0+j-k = (NF-FT) + (FT-k+j)
            if (g0 + j < GTOT) {
                f4a v;
                #pragma unroll
                for (int m = 0; m < 4; ++m) {
                    const int rl = rq * 4 + m;
                    float a = 0.f;
                    #pragma unroll
                    for (int k = 1; k < 4; ++k)
                        a += (k > j) ? L[s][k][rl][FT - k + j] : 0.f;
                    v[m] = a;
                }
                *reinterpret_cast<f4a*>(&yb[(size_t)(g0 + j) * HOP + rbase + rq * 4]) = v;
            }
        }
    };

    // ---- prologue: 2 items in flight ----
    fill(0, 0);
    if (T > 1) fill(1, 1);

    // ---- steady-state loop: one barrier per item, counted vmcnt ----
    for (int t = 0; t < T; ++t) {
        if (t + 2 < T) fill(t + 2, (t + 2) & 3);
        // 8 newest VMEM ops = items t+1,t+2's DMAs -> everything older
        // (item t's DMAs) retired. Tail reduces the count.
        if (t + 2 < T)      asm volatile("s_waitcnt vmcnt(8)" ::: "memory");
        else if (t + 1 < T) asm volatile("s_waitcnt vmcnt(4)" ::: "memory");
        else                asm volatile("s_waitcnt vmcnt(0)" ::: "memory");
        asm volatile("s_barrier" ::: "memory");
        phase2(t, t & 3);
    }
}

extern "C" void kernel_launch(void* const* d_in, const int* in_sizes, int n_in,
                              void* d_out, int out_size, void* d_ws, size_t ws_size,
                              hipStream_t stream) {
    const float* x = (const float*)d_in[0];
    float* y = (float*)d_out;
    oadd_kernel<<<dim3(NBLK), 256, 0, stream>>>(x, y);
}